// Round 2
// baseline (191.842 us; speedup 1.0000x reference)
//
#include <hip/hip_runtime.h>

#define H 768
#define W 768
#define TILE 32
#define RREG 48          // x,y region = TILE + 16
#define RAB 40           // A,b plane = TILE + 8
#define RADIUS 4
#define PLANE_STRIDE (H * W)

__global__ __launch_bounds__(256) void guided_filter_fused(
    const float* __restrict__ xg, const float* __restrict__ yg,
    float* __restrict__ outg)
{
    // Shared memory layout (total 63424 B <= 64KB):
    __shared__ float sX[RREG][RREG + 1];   // 48x49
    __shared__ float sY[RREG][RREG + 1];
    __shared__ float sA[RAB][RAB + 1];     // 40x41
    __shared__ float sB[RAB][RAB + 1];
    __shared__ union {
        struct { float h0[RREG][RAB + 1], h1[RREG][RAB + 1],
                       h2[RREG][RAB + 1], h3[RREG][RAB + 1]; } p1; // 48x41 x4
        struct { float hA[RAB][TILE + 1], hB[RAB][TILE + 1]; } p2; // 40x33 x2
    } u;

    const int tid   = threadIdx.x;
    const int tileX = blockIdx.x;
    const int tileY = blockIdx.y;
    const int plane = blockIdx.z;

    const int r0 = tileY * TILE - 8;   // region origin (image coords)
    const int c0 = tileX * TILE - 8;

    const float* xp = xg + (size_t)plane * PLANE_STRIDE;
    const float* yp = yg + (size_t)plane * PLANE_STRIDE;
    float*      op  = outg + (size_t)plane * PLANE_STRIDE;

    // ---- Phase 0: load x, y region (zero outside image) ----
    for (int i = tid; i < RREG * RREG; i += 256) {
        int rr = i / RREG, cc = i % RREG;
        int gr = r0 + rr, gc = c0 + cc;
        bool in = (gr >= 0) & (gr < H) & (gc >= 0) & (gc < W);
        float xv = 0.f, yv = 0.f;
        if (in) {
            int gidx = gr * W + gc;
            xv = xp[gidx];
            yv = yp[gidx];
        }
        sX[rr][cc] = xv;
        sY[rr][cc] = yv;
    }
    __syncthreads();

    // ---- Phase 1: horizontal 9-tap sums of x, y, xy, xx (sliding) ----
    // h-plane: rows 0..47 (region rows), cols 0..39 (h col hc -> region col hc+4)
    if (tid < 240) {
        int rr  = tid % RREG;          // 0..47
        int seg = tid / RREG;          // 0..4, 8 cols each
        int hc0 = seg * 8;
        float ax = 0.f, ay = 0.f, axy = 0.f, axx = 0.f;
#pragma unroll
        for (int d = 0; d < 9; ++d) {
            float xv = sX[rr][hc0 + d], yv = sY[rr][hc0 + d];
            ax += xv; ay += yv; axy += xv * yv; axx += xv * xv;
        }
        u.p1.h0[rr][hc0] = ax; u.p1.h1[rr][hc0] = ay;
        u.p1.h2[rr][hc0] = axy; u.p1.h3[rr][hc0] = axx;
#pragma unroll
        for (int j = 1; j < 8; ++j) {
            int hc = hc0 + j;
            float xn = sX[rr][hc + 8], yn = sY[rr][hc + 8];
            float xo = sX[rr][hc - 1], yo = sY[rr][hc - 1];
            ax += xn - xo; ay += yn - yo;
            axy += xn * yn - xo * yo;
            axx += xn * xn - xo * xo;
            u.p1.h0[rr][hc] = ax; u.p1.h1[rr][hc] = ay;
            u.p1.h2[rr][hc] = axy; u.p1.h3[rr][hc] = axx;
        }
    }
    __syncthreads();

    // ---- Phase 2: vertical 9-tap sums -> A, b (sliding down columns) ----
    // plane (pr,pc) -> image pixel (r0+4+pr, c0+4+pc); window = h-rows pr..pr+8
    // A,b are defined ONLY at in-image pixels; outside => exactly 0 (zero pad
    // of box(A) in the reference). Without this mask, edge-tile halo positions
    // whose 9x9 window touches the image get spurious nonzero A,b.
    if (tid < 240) {
        int pc  = tid % RAB;           // 0..39
        int seg = tid / RAB;           // 0..5, 7 rows each (last 5)
        int pr0 = seg * 7;
        int prE = pr0 + 7; if (prE > RAB) prE = RAB;
        float vx = 0.f, vy = 0.f, vxy = 0.f, vxx = 0.f;
#pragma unroll
        for (int d = 0; d < 9; ++d) {
            vx  += u.p1.h0[pr0 + d][pc];
            vy  += u.p1.h1[pr0 + d][pc];
            vxy += u.p1.h2[pr0 + d][pc];
            vxx += u.p1.h3[pr0 + d][pc];
        }
        for (int pr = pr0; pr < prE; ++pr) {
            int ir = r0 + 4 + pr, ic = c0 + 4 + pc;
            bool inimg = (ir >= 0) & (ir < H) & (ic >= 0) & (ic < W);
            int ch = min(ir + RADIUS, H - 1) - max(ir - RADIUS, 0) + 1;
            int cw = min(ic + RADIUS, W - 1) - max(ic - RADIUS, 0) + 1;
            float invN = 1.0f / (float)(ch * cw);
            float mx = vx * invN, my = vy * invN;
            float cov = vxy * invN - mx * my;
            float vr  = vxx * invN - mx * mx;
            float Av = cov / (vr + 0.1f);
            float Bv = my - Av * mx;
            sA[pr][pc] = inimg ? Av : 0.0f;
            sB[pr][pc] = inimg ? Bv : 0.0f;
            if (pr + 1 < prE) {
                vx  += u.p1.h0[pr + 9][pc] - u.p1.h0[pr][pc];
                vy  += u.p1.h1[pr + 9][pc] - u.p1.h1[pr][pc];
                vxy += u.p1.h2[pr + 9][pc] - u.p1.h2[pr][pc];
                vxx += u.p1.h3[pr + 9][pc] - u.p1.h3[pr][pc];
            }
        }
    }
    __syncthreads();

    // ---- Phase 3: horizontal 9-tap sums of A, b (sliding) ----
    // hA/hB rows = plane rows 0..39, cols oc 0..31 (-> plane col oc+4)
    if (tid < 240) {
        int pr  = tid % RAB;           // 0..39
        int seg = tid / RAB;           // 0..5, 6 cols each (last 2)
        int oc0 = seg * 6;
        int ocE = oc0 + 6; if (ocE > TILE) ocE = TILE;
        float aa = 0.f, bb = 0.f;
#pragma unroll
        for (int d = 0; d < 9; ++d) {
            aa += sA[pr][oc0 + d];
            bb += sB[pr][oc0 + d];
        }
        for (int oc = oc0; oc < ocE; ++oc) {
            u.p2.hA[pr][oc] = aa;
            u.p2.hB[pr][oc] = bb;
            if (oc + 1 < ocE) {
                aa += sA[pr][oc + 9] - sA[pr][oc];
                bb += sB[pr][oc + 9] - sB[pr][oc];
            }
        }
    }
    __syncthreads();

    // ---- Phase 4: vertical 9-tap sums of A, b + final out ----
    {
        int q   = tid % TILE;          // 0..31
        int seg = tid / TILE;          // 0..7, 4 rows each
        int o0  = seg * 4;
        float aa = 0.f, bb = 0.f;
#pragma unroll
        for (int d = 0; d < 9; ++d) {
            aa += u.p2.hA[o0 + d][q];
            bb += u.p2.hB[o0 + d][q];
        }
        for (int o = o0; o < o0 + 4; ++o) {
            int ir = r0 + 8 + o, ic = c0 + 8 + q;   // always in image
            int ch = min(ir + RADIUS, H - 1) - max(ir - RADIUS, 0) + 1;
            int cw = min(ic + RADIUS, W - 1) - max(ic - RADIUS, 0) + 1;
            float invN = 1.0f / (float)(ch * cw);
            float mA = aa * invN, mB = bb * invN;
            op[ir * W + ic] = mA * sX[8 + o][8 + q] + mB;
            if (o + 1 < o0 + 4) {
                aa += u.p2.hA[o + 9][q] - u.p2.hA[o][q];
                bb += u.p2.hB[o + 9][q] - u.p2.hB[o][q];
            }
        }
    }
}

extern "C" void kernel_launch(void* const* d_in, const int* in_sizes, int n_in,
                              void* d_out, int out_size, void* d_ws, size_t ws_size,
                              hipStream_t stream) {
    const float* x = (const float*)d_in[0];
    const float* y = (const float*)d_in[1];
    float* out = (float*)d_out;

    dim3 grid(W / TILE, H / TILE, 24);   // 24 x 24 tiles, 8*3 = 24 planes
    dim3 block(256);
    hipLaunchKernelGGL(guided_filter_fused, grid, block, 0, stream, x, y, out);
}

// Round 3
// 107.515 us; speedup vs baseline: 1.7843x; 1.7843x over previous
//
#include <hip/hip_runtime.h>

#define H 768
#define W 768
#define SW 256        // output cols per strip
#define RW 272        // x,y region width (SW + 16)
#define ABWID 264     // A,b row width (SW + 8)
#define ROWS 64       // output rows per block
#define STEPS 80      // ROWS + 16 pipeline fill
#define RADIUS 4

__global__ __launch_bounds__(256, 4) void gf_stream(
    const float* __restrict__ xg, const float* __restrict__ yg,
    float* __restrict__ outg)
{
    __shared__ float2 xyrow[RW];        // newest x,y row        (2176 B)
    __shared__ float  xring[9][RW];     // 9-deep x ring (out)   (9792 B)
    __shared__ float2 abrow[ABWID];     // current A,b row       (2112 B)
    __shared__ float4 tring[9][8];      // h-ring for 8 extra A-cols (1152 B)

    const int t     = threadIdx.x;
    const int strip = blockIdx.x;   // 0..2
    const int band  = blockIdx.y;   // 0..11
    const int plane = blockIdx.z;   // 0..23
    const int base  = strip * SW;
    const int R0    = band * ROWS;

    const float* xp = xg + (size_t)plane * (H * W);
    const float* yp = yg + (size_t)plane * (H * W);
    float*       op = outg + (size_t)plane * (H * W);

    // ---- per-thread column geometry (constant over steps) ----
    // main A-col: region col t+4 -> abs col
    const int  a_abs   = base + t - 4;
    const bool a_colok = (a_abs >= 0) && (a_abs < W);
    const float invCwA = a_colok
        ? 1.0f / (float)(min(a_abs + RADIUS, W - 1) - max(a_abs - RADIUS, 0) + 1) : 0.f;
    // extra A-col for t<8: region col 260+t -> abs col
    const int  a2_abs   = base + 252 + t;
    const bool a2_colok = (t < 8) && (a2_abs < W);
    const float invCwA2 = a2_colok
        ? 1.0f / (float)(min(a2_abs + RADIUS, W - 1) - max(a2_abs - RADIUS, 0) + 1) : 0.f;
    // out col (always in image)
    const int   c_abs  = base + t;
    const float invCwO = 1.0f / (float)(min(c_abs + RADIUS, W - 1) - max(c_abs - RADIUS, 0) + 1);
    // load cols: region col t (and 256+t for t<16)
    const int  lc1   = base + t - 8;
    const bool lc1ok = (lc1 >= 0) && (lc1 < W);
    const int  lc2   = base + 248 + t;          // = base + (256+t) - 8
    const bool lc2ok = (t < 16) && (lc2 < W);   // lc2 >= 0 always (base>=0, +248)

    // ---- register rings (static indices via unroll-9) ----
    float hx[9], hy[9], hxy[9], hxx[9];   // x-stage h history, col a_abs
    float hA9[9], hB9[9];                 // AB-stage h history, col c_abs
#pragma unroll
    for (int i = 0; i < 9; ++i) { hx[i] = hy[i] = hxy[i] = hxx[i] = 0.f; hA9[i] = hB9[i] = 0.f; }
    float vx = 0.f, vy = 0.f, vxy = 0.f, vxx = 0.f;       // vertical sums, col a_abs
    float v2x = 0.f, v2y = 0.f, v2xy = 0.f, v2xx = 0.f;   // vertical sums, extra col
    float vA = 0.f, vB = 0.f;                             // vertical sums of hA,hB

    // zero the tiny LDS h-ring (read-before-write during warmup)
    if (t < 72) ((float4*)tring)[t] = make_float4(0.f, 0.f, 0.f, 0.f);

    // ---- preload row for s=0: image row R0-8 ----
    float gx, gy, gx2, gy2;
    {
        int gr = R0 - 8;                 // <= 696, may be < 0
        bool rok = (gr >= 0);
        const float* xr = xp + gr * W;
        const float* yr = yp + gr * W;
        gx  = (rok && lc1ok) ? xr[lc1] : 0.f;
        gy  = (rok && lc1ok) ? yr[lc1] : 0.f;
        gx2 = (rok && lc2ok) ? xr[lc2] : 0.f;
        gy2 = (rok && lc2ok) ? yr[lc2] : 0.f;
    }

    for (int so = 0; so < STEPS; so += 9) {
#pragma unroll
        for (int oo = 0; oo < 9; ++oo) {
            const int s = so + oo;               // so%9==0 -> ring slot = oo (static)
            if (s < STEPS) {
                const int r = R0 - 16 + s;       // output row this step

                __syncthreads();  // prev step's reads of xyrow/xring/abrow done

                // -- write current row (row r+8) to LDS --
                const int wr = (r + 8) % 9;      // uniform scalar
                xyrow[t] = make_float2(gx, gy);
                xring[wr][t] = gx;
                if (t < 16) {
                    xyrow[256 + t] = make_float2(gx2, gy2);
                    xring[wr][256 + t] = gx2;
                }
                // -- prefetch next step's row (r+9): latency hidden under step --
                {
                    int gr = r + 9;
                    bool rok = (gr >= 0) && (gr < H);
                    const float* xr = xp + gr * W;
                    const float* yr = yp + gr * W;
                    gx  = (rok && lc1ok) ? xr[lc1] : 0.f;
                    gy  = (rok && lc1ok) ? yr[lc1] : 0.f;
                    gx2 = (rok && lc2ok) ? xr[lc2] : 0.f;
                    gy2 = (rok && lc2ok) ? yr[lc2] : 0.f;
                }

                __syncthreads();  // xyrow/xring visible

                // -- NH: horizontal 9-tap of x,y,xy,xx at region cols t..t+8 --
                float nx = 0.f, ny = 0.f, nxy = 0.f, nxx = 0.f;
#pragma unroll
                for (int d = 0; d < 9; ++d) {
                    float2 v = xyrow[t + d];
                    nx += v.x; ny += v.y; nxy += v.x * v.y; nxx += v.x * v.x;
                }
                vx  += nx  - hx[oo];  hx[oo]  = nx;
                vy  += ny  - hy[oo];  hy[oo]  = ny;
                vxy += nxy - hxy[oo]; hxy[oo] = nxy;
                vxx += nxx - hxx[oo]; hxx[oo] = nxx;

                // -- A,b at image row ra = r+4, col a_abs --
                const int ra = r + 4;
                const bool rowok = (s >= 8) && (ra >= 0) && (ra < H);
                const float invChA = rowok
                    ? 1.0f / (float)(min(ra + RADIUS, H - 1) - max(ra - RADIUS, 0) + 1) : 0.f;
                float Aout = 0.f, Bout = 0.f;
                if (rowok && a_colok) {
                    float invN = invChA * invCwA;
                    float mx = vx * invN, my = vy * invN;
                    float cov = vxy * invN - mx * my;
                    float vr  = vxx * invN - mx * mx;
                    Aout = cov / (vr + 0.1f);
                    Bout = my - Aout * mx;
                }
                abrow[t] = make_float2(Aout, Bout);

                // -- extra A-cols (region 260..267) handled by t<8 via LDS ring --
                if (t < 8) {
                    float ex = 0.f, ey = 0.f, exy = 0.f, exx = 0.f;
#pragma unroll
                    for (int d = 0; d < 9; ++d) {
                        float2 v = xyrow[256 + t + d];
                        ex += v.x; ey += v.y; exy += v.x * v.y; exx += v.x * v.x;
                    }
                    float4 old = tring[oo][t];
                    v2x += ex - old.x; v2y += ey - old.y;
                    v2xy += exy - old.z; v2xx += exx - old.w;
                    tring[oo][t] = make_float4(ex, ey, exy, exx);
                    float A2 = 0.f, B2 = 0.f;
                    if (rowok && a2_colok) {
                        float invN = invChA * invCwA2;
                        float mx = v2x * invN, my = v2y * invN;
                        float cov = v2xy * invN - mx * my;
                        float vr  = v2xx * invN - mx * mx;
                        A2 = cov / (vr + 0.1f);
                        B2 = my - A2 * mx;
                    }
                    abrow[256 + t] = make_float2(A2, B2);
                }

                __syncthreads();  // abrow visible

                // -- O: horizontal 9-tap of A,b at row-rel cols t..t+8 --
                float hAn = 0.f, hBn = 0.f;
#pragma unroll
                for (int d = 0; d < 9; ++d) {
                    float2 v = abrow[t + d];
                    hAn += v.x; hBn += v.y;
                }
                vA += hAn - hA9[oo]; hA9[oo] = hAn;
                vB += hBn - hB9[oo]; hB9[oo] = hBn;

                if (s >= 16) {       // r in [R0, R0+ROWS)
                    float xo = xring[r % 9][t + 8];   // x at (r, c_abs)
                    const float invChO =
                        1.0f / (float)(min(r + RADIUS, H - 1) - max(r - RADIUS, 0) + 1);
                    float invN2 = invChO * invCwO;
                    op[r * W + c_abs] = (vA * invN2) * xo + (vB * invN2);
                }
            }
        }
    }
}

extern "C" void kernel_launch(void* const* d_in, const int* in_sizes, int n_in,
                              void* d_out, int out_size, void* d_ws, size_t ws_size,
                              hipStream_t stream) {
    const float* x = (const float*)d_in[0];
    const float* y = (const float*)d_in[1];
    float* out = (float*)d_out;

    dim3 grid(W / SW, H / ROWS, 24);   // 3 strips x 12 bands x 24 planes = 864 blocks
    dim3 block(256);
    hipLaunchKernelGGL(gf_stream, grid, block, 0, stream, x, y, out);
}

// Round 4
// 103.824 us; speedup vs baseline: 1.8478x; 1.0356x over previous
//
#include <hip/hip_runtime.h>

#define H 768
#define W 768
#define SW 256        // output cols per strip
#define RW 272        // xy region width (SW + 16)
#define ABW 264       // A,b row width (SW + 8)
#define ROWS 64       // output rows per band
#define NSTEP 40      // double-row steps: (ROWS + 16)/2
#define RADIUS 4

__global__ __launch_bounds__(256, 4) void gf_stream2(
    const float* __restrict__ xg, const float* __restrict__ yg,
    float* __restrict__ outg)
{
    // Double-buffered row storage -> ONE barrier per step.
    __shared__ float2 xybuf[2][2][RW];   // [parity][row-in-step][col]  8704 B
    __shared__ float2 abbuf[2][2][ABW];  //                            8448 B
    __shared__ float4 tring[9][8];       // extra-col h-ring (t<8 RMW) 1152 B

    const int t     = threadIdx.x;
    const int base  = blockIdx.x * SW;
    const int R0    = blockIdx.y * ROWS;
    const int plane = blockIdx.z;

    const float* xp = xg + (size_t)plane * (H * W);
    const float* yp = yg + (size_t)plane * (H * W);
    float*       op = outg + (size_t)plane * (H * W);

    // ---- per-thread column geometry (loop-invariant) ----
    const int  a_abs   = base + t - 4;                  // main A-col
    const bool a_colok = (a_abs >= 0) && (a_abs < W);
    const float invCwA = a_colok
        ? 1.0f / (float)(min(a_abs + RADIUS, W - 1) - max(a_abs - RADIUS, 0) + 1) : 0.f;
    const int  a2_abs   = base + 252 + t;               // extra A-col (t<8)
    const bool a2_colok = (t < 8) && (a2_abs < W);
    const float invCwA2 = a2_colok
        ? 1.0f / (float)(min(a2_abs + RADIUS, W - 1) - max(a2_abs - RADIUS, 0) + 1) : 0.f;
    const int   c_abs  = base + t;                      // output col
    const float invCwO = 1.0f / (float)(min(c_abs + RADIUS, W - 1) - max(c_abs - RADIUS, 0) + 1);
    const int  lc1   = base + t - 8;                    // load col (region col t)
    const bool lc1ok = (lc1 >= 0) && (lc1 < W);
    const int  lc2   = base + 248 + t;                  // load col (region col 256+t), t<16
    const bool lc2ok = (t < 16) && (lc2 < W);

    // ---- register rings, static mod-9 indexing via unroll ----
    float hx[9], hy[9], hxy[9], hxx[9];   // h-sums of x,y,xy,xx (col a_abs)
    float hA9[9], hB9[9];                 // h-sums of A,b (col c_abs)
#pragma unroll
    for (int i = 0; i < 9; ++i) { hx[i]=hy[i]=hxy[i]=hxx[i]=0.f; hA9[i]=hB9[i]=0.f; }
    float vx=0.f, vy=0.f, vxy=0.f, vxx=0.f;       // vertical sums (col a_abs)
    float v2x=0.f, v2y=0.f, v2xy=0.f, v2xx=0.f;   // vertical sums (extra col)
    float vA=0.f, vB=0.f;                         // vertical sums of hA,hB

    if (t < 72) ((float4*)tring)[t] = make_float4(0.f,0.f,0.f,0.f);

    // ---- prologue: xybuf[0] <- xy rows R0-8, R0-7 ; prefetch rows R0-6, R0-5 ----
    {
        int g0 = R0 - 8, g1 = R0 - 7;
        bool k0 = (g0 >= 0), k1 = (g1 >= 0);
        const float *x0 = xp + g0 * W, *y0 = yp + g0 * W;
        const float *x1 = xp + g1 * W, *y1 = yp + g1 * W;
        float a, b;
        a = (k0 && lc1ok) ? x0[lc1] : 0.f;  b = (k0 && lc1ok) ? y0[lc1] : 0.f;
        xybuf[0][0][t] = make_float2(a, b);
        a = (k1 && lc1ok) ? x1[lc1] : 0.f;  b = (k1 && lc1ok) ? y1[lc1] : 0.f;
        xybuf[0][1][t] = make_float2(a, b);
        if (t < 16) {
            a = (k0 && lc2ok) ? x0[lc2] : 0.f;  b = (k0 && lc2ok) ? y0[lc2] : 0.f;
            xybuf[0][0][256 + t] = make_float2(a, b);
            a = (k1 && lc2ok) ? x1[lc2] : 0.f;  b = (k1 && lc2ok) ? y1[lc2] : 0.f;
            xybuf[0][1][256 + t] = make_float2(a, b);
        }
    }
    float p0x, p0y, p0x2, p0y2, p1x, p1y, p1x2, p1y2;
    {
        int g0 = R0 - 6, g1 = R0 - 5;
        bool k0 = (g0 >= 0), k1 = (g1 >= 0);
        const float *x0 = xp + g0 * W, *y0 = yp + g0 * W;
        const float *x1 = xp + g1 * W, *y1 = yp + g1 * W;
        p0x  = (k0 && lc1ok) ? x0[lc1] : 0.f;  p0y  = (k0 && lc1ok) ? y0[lc1] : 0.f;
        p1x  = (k1 && lc1ok) ? x1[lc1] : 0.f;  p1y  = (k1 && lc1ok) ? y1[lc1] : 0.f;
        p0x2 = (k0 && lc2ok) ? x0[lc2] : 0.f;  p0y2 = (k0 && lc2ok) ? y0[lc2] : 0.f;
        p1x2 = (k1 && lc2ok) ? x1[lc2] : 0.f;  p1y2 = (k1 && lc2ok) ? y1[lc2] : 0.f;
    }
    __syncthreads();

    for (int S0 = 0; S0 < NSTEP; S0 += 9) {
#pragma unroll
        for (int u = 0; u < 9; ++u) {
            const int S = S0 + u;
            if (S < NSTEP) {
                const int r0  = R0 - 16 + 2 * S;    // output row j=0 this step
                const int cur = S & 1, nxt = cur ^ 1;

                // -- W: publish rows r0+10, r0+11 (prefetched last step) --
                xybuf[nxt][0][t] = make_float2(p0x, p0y);
                xybuf[nxt][1][t] = make_float2(p1x, p1y);
                if (t < 16) {
                    xybuf[nxt][0][256 + t] = make_float2(p0x2, p0y2);
                    xybuf[nxt][1][256 + t] = make_float2(p1x2, p1y2);
                }
                // -- prefetch rows r0+12, r0+13 (used at W of step S+1) --
                {
                    int g0 = r0 + 12, g1 = r0 + 13;
                    bool k0 = (g0 >= 0) && (g0 < H);
                    bool k1 = (g1 >= 0) && (g1 < H);
                    const float *x0 = xp + g0 * W, *y0 = yp + g0 * W;
                    const float *x1 = xp + g1 * W, *y1 = yp + g1 * W;
                    p0x  = (k0 && lc1ok) ? x0[lc1] : 0.f;  p0y  = (k0 && lc1ok) ? y0[lc1] : 0.f;
                    p1x  = (k1 && lc1ok) ? x1[lc1] : 0.f;  p1y  = (k1 && lc1ok) ? y1[lc1] : 0.f;
                    p0x2 = (k0 && lc2ok) ? x0[lc2] : 0.f;  p0y2 = (k0 && lc2ok) ? y0[lc2] : 0.f;
                    p1x2 = (k1 && lc2ok) ? x1[lc2] : 0.f;  p1y2 = (k1 && lc2ok) ? y1[lc2] : 0.f;
                }
                // -- x at output rows (L2 hit: fetched ~4 steps ago); used post-barrier --
                float xq0 = (r0 >= 0)     ? xp[r0 * W + c_abs]       : 0.f;
                float xq1 = (r0 + 1 >= 0) ? xp[(r0 + 1) * W + c_abs] : 0.f;

                // ================= j = 0 : xy row r0+8 =================
                {
                    const int sl = (2 * u) % 9;
                    float nx=0.f, ny=0.f, nxy=0.f, nxx=0.f;
#pragma unroll
                    for (int d = 0; d < 9; ++d) {
                        float2 v = xybuf[cur][0][t + d];
                        nx += v.x; ny += v.y; nxy += v.x * v.y; nxx += v.x * v.x;
                    }
                    vx  += nx  - hx[sl];  hx[sl]  = nx;
                    vy  += ny  - hy[sl];  hy[sl]  = ny;
                    vxy += nxy - hxy[sl]; hxy[sl] = nxy;
                    vxx += nxx - hxx[sl]; hxx[sl] = nxx;

                    const int ra = r0 + 4;
                    const bool rowok = (S >= 4) && (ra >= 0) && (ra < H);
                    float Aout = 0.f, Bout = 0.f;
                    if (rowok && a_colok) {
                        const float invCh = 1.0f /
                            (float)(min(ra + RADIUS, H - 1) - max(ra - RADIUS, 0) + 1);
                        float invN = invCh * invCwA;
                        float mx = vx * invN, my = vy * invN;
                        float cov = vxy * invN - mx * my;
                        float vr  = vxx * invN - mx * mx;
                        float Ai = cov * __builtin_amdgcn_rcpf(vr + 0.1f);
                        Aout = Ai; Bout = my - Ai * mx;
                    }
                    abbuf[cur][0][t] = make_float2(Aout, Bout);
                }
                // ================= j = 1 : xy row r0+9 =================
                {
                    const int sl = (2 * u + 1) % 9;
                    float nx=0.f, ny=0.f, nxy=0.f, nxx=0.f;
#pragma unroll
                    for (int d = 0; d < 9; ++d) {
                        float2 v = xybuf[cur][1][t + d];
                        nx += v.x; ny += v.y; nxy += v.x * v.y; nxx += v.x * v.x;
                    }
                    vx  += nx  - hx[sl];  hx[sl]  = nx;
                    vy  += ny  - hy[sl];  hy[sl]  = ny;
                    vxy += nxy - hxy[sl]; hxy[sl] = nxy;
                    vxx += nxx - hxx[sl]; hxx[sl] = nxx;

                    const int ra = r0 + 5;
                    const bool rowok = (S >= 4) && (ra >= 0) && (ra < H);
                    float Aout = 0.f, Bout = 0.f;
                    if (rowok && a_colok) {
                        const float invCh = 1.0f /
                            (float)(min(ra + RADIUS, H - 1) - max(ra - RADIUS, 0) + 1);
                        float invN = invCh * invCwA;
                        float mx = vx * invN, my = vy * invN;
                        float cov = vxy * invN - mx * my;
                        float vr  = vxx * invN - mx * mx;
                        float Ai = cov * __builtin_amdgcn_rcpf(vr + 0.1f);
                        Aout = Ai; Bout = my - Ai * mx;
                    }
                    abbuf[cur][1][t] = make_float2(Aout, Bout);
                }
                // ======= extra A-cols 252..259 rel base (lanes t<8, same-lane RMW ring) =======
                if (t < 8) {
#pragma unroll
                    for (int j = 0; j < 2; ++j) {
                        const int sl = (2 * u + j) % 9;
                        float ex=0.f, ey=0.f, exy=0.f, exx=0.f;
#pragma unroll
                        for (int d = 0; d < 9; ++d) {
                            float2 v = xybuf[cur][j][256 + t + d];
                            ex += v.x; ey += v.y; exy += v.x * v.y; exx += v.x * v.x;
                        }
                        float4 old = tring[sl][t];
                        v2x += ex - old.x; v2y += ey - old.y;
                        v2xy += exy - old.z; v2xx += exx - old.w;
                        tring[sl][t] = make_float4(ex, ey, exy, exx);

                        const int ra = r0 + 4 + j;
                        const bool rowok = (S >= 4) && (ra >= 0) && (ra < H);
                        float A2 = 0.f, B2 = 0.f;
                        if (rowok && a2_colok) {
                            const float invCh = 1.0f /
                                (float)(min(ra + RADIUS, H - 1) - max(ra - RADIUS, 0) + 1);
                            float invN = invCh * invCwA2;
                            float mx = v2x * invN, my = v2y * invN;
                            float cov = v2xy * invN - mx * my;
                            float vr  = v2xx * invN - mx * mx;
                            float Ai = cov * __builtin_amdgcn_rcpf(vr + 0.1f);
                            A2 = Ai; B2 = my - Ai * mx;
                        }
                        abbuf[cur][j][256 + t] = make_float2(A2, B2);
                    }
                }

                __syncthreads();   // the ONLY barrier: abbuf (and next xybuf) published

                // ================= O : output rows r0, r0+1 =================
                {
                    const int sl = (2 * u) % 9;
                    float hA=0.f, hB=0.f;
#pragma unroll
                    for (int d = 0; d < 9; ++d) {
                        float2 v = abbuf[cur][0][t + d];
                        hA += v.x; hB += v.y;
                    }
                    vA += hA - hA9[sl]; hA9[sl] = hA;
                    vB += hB - hB9[sl]; hB9[sl] = hB;
                    if (S >= 8) {
                        const float invCh = 1.0f /
                            (float)(min(r0 + RADIUS, H - 1) - max(r0 - RADIUS, 0) + 1);
                        float invN = invCh * invCwO;
                        op[r0 * W + c_abs] = (vA * invN) * xq0 + (vB * invN);
                    }
                }
                {
                    const int sl = (2 * u + 1) % 9;
                    float hA=0.f, hB=0.f;
#pragma unroll
                    for (int d = 0; d < 9; ++d) {
                        float2 v = abbuf[cur][1][t + d];
                        hA += v.x; hB += v.y;
                    }
                    vA += hA - hA9[sl]; hA9[sl] = hA;
                    vB += hB - hB9[sl]; hB9[sl] = hB;
                    if (S >= 8) {
                        const int r = r0 + 1;
                        const float invCh = 1.0f /
                            (float)(min(r + RADIUS, H - 1) - max(r - RADIUS, 0) + 1);
                        float invN = invCh * invCwO;
                        op[r * W + c_abs] = (vA * invN) * xq1 + (vB * invN);
                    }
                }
            }
        }
    }
}

extern "C" void kernel_launch(void* const* d_in, const int* in_sizes, int n_in,
                              void* d_out, int out_size, void* d_ws, size_t ws_size,
                              hipStream_t stream) {
    const float* x = (const float*)d_in[0];
    const float* y = (const float*)d_in[1];
    float* out = (float*)d_out;

    dim3 grid(W / SW, H / ROWS, 24);   // 3 x 12 x 24 = 864 blocks
    dim3 block(256);
    hipLaunchKernelGGL(gf_stream2, grid, block, 0, stream, x, y, out);
}